// Round 7
// baseline (1192.470 us; speedup 1.0000x reference)
//
#include <hip/hip_runtime.h>
#include <hip/hip_cooperative_groups.h>
#include <stdint.h>

namespace cg = cooperative_groups;

#define DEV static __device__ __forceinline__

typedef unsigned short u16;
typedef __attribute__((ext_vector_type(8))) short s16x8;   // 8 x bf16 (4 VGPRs), MFMA A/B frag
typedef __attribute__((ext_vector_type(4))) float f32x4;   // MFMA C/D frag

// ---------- helpers ----------
DEV u16 f2bf(float x) {                       // fp32 -> bf16, round-to-nearest-even
    uint32_t u = __float_as_uint(x);
    u = u + 0x7FFFu + ((u >> 16) & 1u);
    return (u16)(u >> 16);
}
DEV u16 f2bf_trunc(float x) {                 // truncate; fine for positive P (errors cancel in l)
    return (u16)(__float_as_uint(x) >> 16);
}

DEV f32x4 mfma_bf16(s16x8 a, s16x8 b, f32x4 c) {
    return __builtin_amdgcn_mfma_f32_16x16x32_bf16(a, b, c, 0, 0, 0);
}

// XCD-aware block swizzle (T1) for the fallback path (block→XCD is bid%8).
DEV int swz8(int bid, int nwg) { return (bid & 7) * (nwg >> 3) + (bid >> 3); }

// Problem constants
constexpr int Bq   = 4;
constexpr int S    = 2048;
constexpr int D    = 768;
constexpr int H    = 12;
constexpr int HD   = 64;
constexpr int BS   = Bq * S;          // 8192 rows
constexpr float SC_LOG2 = 0.18033688011112042f;   // 1/sqrt(64) * log2(e)

DEV int4 pack8(float4 a, float4 b) {
    int4 r;
    r.x = (int)((uint32_t)f2bf(a.x) | ((uint32_t)f2bf(a.y) << 16));
    r.y = (int)((uint32_t)f2bf(a.z) | ((uint32_t)f2bf(a.w) << 16));
    r.z = (int)((uint32_t)f2bf(b.x) | ((uint32_t)f2bf(b.y) << 16));
    r.w = (int)((uint32_t)f2bf(b.z) | ((uint32_t)f2bf(b.w) << 16));
    return r;
}

struct MegaArgs {
    const float *q, *k, *v;
    const float *wq, *bq, *wk, *bk, *wv, *bv, *wo, *bo;
    u16 *wqT, *wkT, *wvT, *woT;
    u16 *Qhp, *Khp, *VTp, *CTX;
    float* dout;
};

// ---------- phase body: weight fp32 [K][N] -> bf16 [N][K], 256-thread unit ----------
DEV void dev_wtrans(int utid, int unit, const MegaArgs& a, char* hs) {
    const int z = unit / 144, rem = unit - z * 144;
    const int ky = rem / 12, nx = rem % 12;
    const float* w = (z == 0) ? a.wq : (z == 1) ? a.wk : (z == 2) ? a.wv : a.wo;
    u16*         t = (z == 0) ? a.wqT : (z == 1) ? a.wkT : (z == 2) ? a.wvT : a.woT;
    float* tile = (float*)hs;                  // 64*65*4 = 16640 B (fits 36864 half)
    const int k0 = ky * 64, n0 = nx * 64;
    const int tx = utid & 15, ty = utid >> 4;
#pragma unroll
    for (int rr = 0; rr < 4; rr++) {
        int kl = rr * 16 + ty;
        float4 v = *(const float4*)&w[(size_t)(k0 + kl) * D + n0 + tx * 4];
        tile[kl * 65 + tx * 4 + 0] = v.x;
        tile[kl * 65 + tx * 4 + 1] = v.y;
        tile[kl * 65 + tx * 4 + 2] = v.z;
        tile[kl * 65 + tx * 4 + 3] = v.w;
    }
    __syncthreads();
#pragma unroll
    for (int rr = 0; rr < 4; rr++) {
        int nl = rr * 16 + ty;
        int kl = tx * 4;
        ushort4 o = make_ushort4(f2bf(tile[(kl + 0) * 65 + nl]), f2bf(tile[(kl + 1) * 65 + nl]),
                                 f2bf(tile[(kl + 2) * 65 + nl]), f2bf(tile[(kl + 3) * 65 + nl]));
        *(ushort4*)&t[(size_t)(n0 + nl) * D + k0 + kl] = o;
    }
}

// ---------- phase body: 128x128 bf16 GEMM tile, 256-thread unit ----------
// MODE 0: bf16 split-head out (vt=1 -> V written transposed VT[bh][64][S]).
// MODE 1: fp32 row-major [M][768].
template <int MODE, bool AF32>
DEV void dev_gemm(int utid, int mtile, int ntile, int vt,
                  const void* Ap, const u16* __restrict__ BT,
                  const float* __restrict__ bias, void* dst, char* hs) {
    u16* As = (u16*)hs;                        // [128][72] u16
    u16* Bs = (u16*)(hs + 128 * 72 * 2);       // [128][72] u16
    const int lane = utid & 63;
    const int w = utid >> 6, wm = w >> 1, wn = w & 1;   // 2x2 wave grid, 64x64 each
    const int l16 = lane & 15, lg = lane >> 4;
    const int m0 = mtile * 128, n0 = ntile * 128;
    const int sr = utid >> 3, sp = utid & 7;   // staging: 32 rows x 8 chunks per issue

    f32x4 acc[4][4];
#pragma unroll
    for (int i = 0; i < 4; i++)
#pragma unroll
        for (int j = 0; j < 4; j++) acc[i][j] = f32x4{0.f, 0.f, 0.f, 0.f};

    int4 ar[4], br[4];
    auto load = [&](int k0) {
#pragma unroll
        for (int i = 0; i < 4; i++) {
            if (AF32) {
                const float* Af = (const float*)Ap;
                float4 x = *(const float4*)&Af[(size_t)(m0 + sr + i * 32) * D + k0 + sp * 8];
                float4 y = *(const float4*)&Af[(size_t)(m0 + sr + i * 32) * D + k0 + sp * 8 + 4];
                ar[i] = pack8(x, y);
            } else {
                ar[i] = *(const int4*)&((const u16*)Ap)[(size_t)(m0 + sr + i * 32) * D + k0 + sp * 8];
            }
            br[i] = *(const int4*)&BT[(size_t)(n0 + sr + i * 32) * D + k0 + sp * 8];
        }
    };
    load(0);
    for (int t = 0; t < 12; t++) {             // 768 / 64 K-steps
        __syncthreads();
#pragma unroll
        for (int i = 0; i < 4; i++) {
            *(int4*)&As[(sr + i * 32) * 72 + sp * 8] = ar[i];
            *(int4*)&Bs[(sr + i * 32) * 72 + sp * 8] = br[i];
        }
        __syncthreads();
        if (t < 11) load((t + 1) * 64);        // prefetch next K-tile
#pragma unroll
        for (int kk = 0; kk < 2; kk++) {
            s16x8 af[4], bf[4];
#pragma unroll
            for (int mf = 0; mf < 4; mf++)
                af[mf] = *(const s16x8*)&As[(wm * 64 + mf * 16 + l16) * 72 + kk * 32 + lg * 8];
#pragma unroll
            for (int nf = 0; nf < 4; nf++)
                bf[nf] = *(const s16x8*)&Bs[(wn * 64 + nf * 16 + l16) * 72 + kk * 32 + lg * 8];
#pragma unroll
            for (int mf = 0; mf < 4; mf++)
#pragma unroll
                for (int nf = 0; nf < 4; nf++) acc[mf][nf] = mfma_bf16(af[mf], bf[nf], acc[mf][nf]);
        }
    }
    // ---- epilogue (C/D frag layout: col = lane&15, row = (lane>>4)*4 + reg) ----
    __syncthreads();                           // As/Bs reads done; hs becomes C-stage
    if (MODE == 0 && vt) {
        // V: stage TRANSPOSED bf16 tile Ct[128 cols][136]
        u16* Ct = (u16*)hs;
#pragma unroll
        for (int nf = 0; nf < 4; nf++) {
            int col = wn * 64 + nf * 16 + l16;
            float bv = bias[n0 + col];
#pragma unroll
            for (int mf = 0; mf < 4; mf++) {
                int row = wm * 64 + mf * 16 + lg * 4;
#pragma unroll
                for (int rp = 0; rp < 2; rp++) {
                    uint32_t pk = (uint32_t)f2bf(acc[mf][nf][rp * 2] + bv) |
                                  ((uint32_t)f2bf(acc[mf][nf][rp * 2 + 1] + bv) << 16);
                    *(uint32_t*)&Ct[col * 136 + row + rp * 2] = pk;
                }
            }
        }
        __syncthreads();
        const int b = m0 >> 11, s0 = m0 & 2047;
#pragma unroll
        for (int i = 0; i < 8; i++) {
            int idx = i * 256 + utid;
            int col = idx >> 4, ch = idx & 15;
            int gcol = n0 + col;
            int h = gcol >> 6, dd = gcol & 63;
            int4 vv = *(const int4*)&Ct[col * 136 + ch * 8];
            *(int4*)&((u16*)dst)[((size_t)(b * H + h) * HD + dd) * S + s0 + ch * 8] = vv;
        }
    } else if (MODE == 0) {
        // Q,K: stage bf16 tile [128][136], write split-head [B,H,S,64]
        u16* Cs = (u16*)hs;
#pragma unroll
        for (int nf = 0; nf < 4; nf++) {
            float bv = bias[n0 + wn * 64 + nf * 16 + l16];
#pragma unroll
            for (int mf = 0; mf < 4; mf++)
#pragma unroll
                for (int rg = 0; rg < 4; rg++)
                    Cs[(wm * 64 + mf * 16 + lg * 4 + rg) * 136 + wn * 64 + nf * 16 + l16] =
                        f2bf(acc[mf][nf][rg] + bv);
        }
        __syncthreads();
#pragma unroll
        for (int i = 0; i < 8; i++) {
            int idx = i * 256 + utid;
            int row = idx >> 4, ch = idx & 15;
            int gm = m0 + row;
            int b = gm >> 11, s = gm & 2047;
            int c = ch * 8;
            int h = (n0 + c) >> 6, dd = c & 63;
            int4 vv = *(const int4*)&Cs[row * 136 + c];
            *(int4*)&((u16*)dst)[(size_t)((b * H + h) * S + s) * HD + dd] = vv;
        }
    } else {
        // fp32 out-proj: stage in two 64-row passes [64][132]
        float* Cf = (float*)hs;
#pragma unroll
        for (int p = 0; p < 2; p++) {
            if (wm == p) {
#pragma unroll
                for (int nf = 0; nf < 4; nf++) {
                    float bv = bias[n0 + wn * 64 + nf * 16 + l16];
#pragma unroll
                    for (int mf = 0; mf < 4; mf++)
#pragma unroll
                        for (int rg = 0; rg < 4; rg++)
                            Cf[(mf * 16 + lg * 4 + rg) * 132 + wn * 64 + nf * 16 + l16] =
                                acc[mf][nf][rg] + bv;
                }
            }
            __syncthreads();
#pragma unroll
            for (int i = 0; i < 8; i++) {
                int idx = i * 256 + utid;
                int row = idx >> 5, ch = idx & 31;
                float4 vv = *(const float4*)&Cf[row * 132 + ch * 4];
                *(float4*)&((float*)dst)[(size_t)(m0 + p * 64 + row) * D + n0 + ch * 4] = vv;
            }
            if (p == 0) __syncthreads();
        }
    }
}

// ---------- phase body: flash attention (no-max softmax), 512-thread unit ----------
DEV void dev_attn(int tid, int f, const u16* __restrict__ Qh, const u16* __restrict__ Kh,
                  const u16* __restrict__ VT, u16* __restrict__ CTX, char* smem) {
    u16* Ks = (u16*)smem;                      // [64][72]  9216 B
    u16* Vs = (u16*)(smem + 9216);             // [64][72]  9216 B
    const int lane = tid & 63, w = tid >> 6;
    u16* Pw = (u16*)(smem + 18432 + w * 4608); // per-wave [32][72]
    const int l16 = lane & 15, lg = lane >> 4;
    const int bh = f >> 3;
    const int q0 = (f & 7) * 256 + w * 32;
    const u16* Qb = Qh + (size_t)bh * S * HD;
    const u16* Kb = Kh + (size_t)bh * S * HD;
    const u16* Vb = VT + (size_t)bh * HD * S;

    s16x8 qf[2][2];
#pragma unroll
    for (int mf = 0; mf < 2; mf++)
#pragma unroll
        for (int kk = 0; kk < 2; kk++)
            qf[mf][kk] = *(const s16x8*)&Qb[(size_t)(q0 + mf * 16 + l16) * HD + kk * 32 + lg * 8];

    f32x4 o[2][5];                             // [..][4] = row sums via ones-column
#pragma unroll
    for (int mf = 0; mf < 2; mf++)
#pragma unroll
        for (int nf = 0; nf < 5; nf++) o[mf][nf] = f32x4{0.f, 0.f, 0.f, 0.f};

    const s16x8 ones = {0x3F80, 0x3F80, 0x3F80, 0x3F80, 0x3F80, 0x3F80, 0x3F80, 0x3F80};

    const int sr = tid >> 3, sp = tid & 7;     // staging: 64 rows x 8 chunks
    int4 krg, vrg;
    auto loadkv = [&](int kv0) {
        krg = *(const int4*)&Kb[(size_t)(kv0 + sr) * HD + sp * 8];
        vrg = *(const int4*)&Vb[(size_t)sr * S + kv0 + sp * 8];
    };
    loadkv(0);
    for (int t = 0; t < S / 64; t++) {
        __syncthreads();
        *(int4*)&Ks[sr * 72 + sp * 8] = krg;
        *(int4*)&Vs[sr * 72 + sp * 8] = vrg;
        __syncthreads();
        if (t < S / 64 - 1) loadkv((t + 1) * 64);

        f32x4 sc[2][4];
#pragma unroll
        for (int mf = 0; mf < 2; mf++)
#pragma unroll
            for (int nf = 0; nf < 4; nf++) sc[mf][nf] = f32x4{0.f, 0.f, 0.f, 0.f};
#pragma unroll
        for (int kk = 0; kk < 2; kk++) {
#pragma unroll
            for (int nf = 0; nf < 4; nf++) {
                s16x8 kf = *(const s16x8*)&Ks[(nf * 16 + l16) * 72 + kk * 32 + lg * 8];
                sc[0][nf] = mfma_bf16(qf[0][kk], kf, sc[0][nf]);
                sc[1][nf] = mfma_bf16(qf[1][kk], kf, sc[1][nf]);
            }
        }
#pragma unroll
        for (int mf = 0; mf < 2; mf++)
#pragma unroll
            for (int nf = 0; nf < 4; nf++)
#pragma unroll
                for (int rg = 0; rg < 4; rg++) {
                    float p = __builtin_amdgcn_exp2f(sc[mf][nf][rg] * SC_LOG2);
                    Pw[(mf * 16 + lg * 4 + rg) * 72 + nf * 16 + l16] = f2bf_trunc(p);
                }
#pragma unroll
        for (int kk = 0; kk < 2; kk++) {
            s16x8 pf[2];
#pragma unroll
            for (int mf = 0; mf < 2; mf++)
                pf[mf] = *(const s16x8*)&Pw[(mf * 16 + l16) * 72 + kk * 32 + lg * 8];
#pragma unroll
            for (int nf = 0; nf < 4; nf++) {
                s16x8 vf = *(const s16x8*)&Vs[(nf * 16 + l16) * 72 + kk * 32 + lg * 8];
                o[0][nf] = mfma_bf16(pf[0], vf, o[0][nf]);
                o[1][nf] = mfma_bf16(pf[1], vf, o[1][nf]);
            }
            o[0][4] = mfma_bf16(pf[0], ones, o[0][4]);
            o[1][4] = mfma_bf16(pf[1], ones, o[1][4]);
        }
    }
    const int b = bh / H, h = bh - b * H;
#pragma unroll
    for (int mf = 0; mf < 2; mf++)
#pragma unroll
        for (int rg = 0; rg < 4; rg++) {
            int gq = q0 + mf * 16 + lg * 4 + rg;
            float inv = 1.0f / o[mf][4][rg];
#pragma unroll
            for (int nf = 0; nf < 4; nf++) {
                int dc = nf * 16 + l16;
                CTX[(size_t)(b * S + gq) * D + h * HD + dc] = f2bf(o[mf][nf][rg] * inv);
            }
        }
}

// ---------- QKV operand resolve ----------
DEV void resolve_qkv(const MegaArgs& a, int gy, const void*& A, const u16*& BT,
                     const float*& bias, void*& dst, int& vt) {
    if (gy == 0)      { A = a.q; BT = a.wqT; bias = a.bq; dst = a.Qhp; vt = 0; }
    else if (gy == 1) { A = a.k; BT = a.wkT; bias = a.bk; dst = a.Khp; vt = 0; }
    else              { A = a.v; BT = a.wvT; bias = a.bv; dst = a.VTp; vt = 1; }
}

DEV void run_qkv_tile(int utid, int f, const MegaArgs& a, char* hs) {
    const int gy = f / 384, r = f - gy * 384;
    const void* A; const u16* BT; const float* bias; void* dst; int vt;
    resolve_qkv(a, gy, A, BT, bias, dst, vt);
    dev_gemm<0, true>(utid, r / 6, r % 6, vt, A, BT, bias, dst, hs);
}

// ---------- THE mega-kernel: all 4 phases, 3 grid barriers, one dispatch ----------
// 512 blocks x 512 threads = exactly 2 blocks/CU (LDS 72KB<=80, VGPR capped 128 by
// launch_bounds(512,4)); cooperative launch guarantees co-residency or errors out.
// Half-block units (hb = bid*2 + tid/256) run 256-thread GEMM/wtrans tiles; the
// "active" conditions are uniform across both halves of a block, so __syncthreads()
// counts always match. XCD of block bid is bid%8 -> hb's XCD = (hb>>1)&7.
__global__ __launch_bounds__(512, 4) void k_mega(MegaArgs a) {
    __shared__ __align__(16) char smem[73728];
    cg::grid_group gg = cg::this_grid();
    const int tid = threadIdx.x, bid = (int)blockIdx.x;
    const int half = tid >> 8, utid = tid & 255;
    const int hb = (bid << 1) | half;
    char* hs = smem + half * 36864;

    // P0: weight transpose+convert (576 units over 1024 half-blocks)
    if (hb < 576) dev_wtrans(utid, hb, a, hs);
    __threadfence(); gg.sync(); __threadfence();

    // P1: QKV GEMM (1152 tiles over 1024 half-blocks; XCD-chunked mapping)
    {
        const int xcd = (hb >> 1) & 7;
        const int widx = ((hb >> 4) << 1) | (hb & 1);      // 0..127 per XCD
        run_qkv_tile(utid, xcd * 144 + widx, a, hs);
        if (hb < 128)                                      // 16 extra tiles per XCD
            run_qkv_tile(utid, xcd * 144 + 128 + widx, a, hs);
    }
    __threadfence(); gg.sync(); __threadfence();

    // P2: flash attention (384 full-block units over 512 blocks)
    if (bid < 384) dev_attn(tid, (bid & 7) * 48 + (bid >> 3), a.Qhp, a.Khp, a.VTp, a.CTX, smem);
    __threadfence(); gg.sync(); __threadfence();

    // P3: out-projection (384 half-block tiles)
    if (hb < 384) {
        const int xcd = (hb >> 1) & 7;
        const int widx = ((hb >> 4) << 1) | (hb & 1);      // 0..47 per XCD
        const int f = xcd * 48 + widx;
        dev_gemm<1, false>(utid, f / 6, f % 6, 0, a.CTX, a.woT, a.bo, a.dout, hs);
    }
}

// ---------- fallback wrappers (r6 four-dispatch pipeline, same device bodies) ----------
__global__ __launch_bounds__(256, 4) void k_wtrans_w(MegaArgs a) {
    __shared__ __align__(16) char s[36864];
    const int unit = (int)blockIdx.z * 144 + (int)blockIdx.y * 12 + (int)blockIdx.x;
    dev_wtrans(threadIdx.x, unit, a, s);
}
__global__ __launch_bounds__(256, 4) void k_gemm_qkv(MegaArgs a) {
    __shared__ __align__(16) char s[36864];
    run_qkv_tile(threadIdx.x, swz8((int)blockIdx.x, (int)gridDim.x), a, s);
}
__global__ __launch_bounds__(512, 2) void k_attn_w(MegaArgs a) {
    __shared__ __align__(16) char s[55296];
    dev_attn(threadIdx.x, swz8((int)blockIdx.x, (int)gridDim.x), a.Qhp, a.Khp, a.VTp, a.CTX, s);
}
__global__ __launch_bounds__(256, 4) void k_gemm_out(MegaArgs a) {
    __shared__ __align__(16) char s[36864];
    const int f = swz8((int)blockIdx.x, (int)gridDim.x);
    dev_gemm<1, false>(threadIdx.x, f / 6, f % 6, 0, a.CTX, a.woT, a.bo, a.dout, s);
}

// ---------- launcher ----------
extern "C" void kernel_launch(void* const* d_in, const int* in_sizes, int n_in,
                              void* d_out, int out_size, void* d_ws, size_t ws_size,
                              hipStream_t stream) {
    char* ws = (char*)d_ws;
    constexpr size_t SZ_ACT = (size_t)BS * D * 2;    // 12,582,912 B
    constexpr size_t SZ_W   = (size_t)D * D * 2;     //  1,179,648 B

    MegaArgs a;
    a.q  = (const float*)d_in[0];
    a.k  = (const float*)d_in[1];
    a.v  = (const float*)d_in[2];
    a.wq = (const float*)d_in[3];  a.bq = (const float*)d_in[4];
    a.wk = (const float*)d_in[5];  a.bk = (const float*)d_in[6];
    a.wv = (const float*)d_in[7];  a.bv = (const float*)d_in[8];
    a.wo = (const float*)d_in[9];  a.bo = (const float*)d_in[10];
    a.wqT = (u16*)(ws);
    a.wkT = (u16*)(ws + 1 * SZ_W);
    a.wvT = (u16*)(ws + 2 * SZ_W);
    a.woT = (u16*)(ws + 3 * SZ_W);
    char* base2 = ws + 4 * SZ_W;
    a.Qhp = (u16*)(base2);
    a.Khp = (u16*)(base2 + SZ_ACT);
    a.VTp = (u16*)(base2 + 2 * SZ_ACT);
    a.CTX = (u16*)(base2 + 3 * SZ_ACT);
    a.dout = (float*)d_out;

    (void)in_sizes; (void)n_in; (void)out_size; (void)ws_size;

    void* kargs[] = { (void*)&a };
    hipError_t e = hipLaunchCooperativeKernel((const void*)k_mega, dim3(512), dim3(512),
                                              kargs, 0, stream);
    if (e != hipSuccess) {
        (void)hipGetLastError();   // clear error state; use the 4-dispatch fallback
        k_wtrans_w<<<dim3(12, 12, 4), 256, 0, stream>>>(a);
        k_gemm_qkv<<<dim3(3 * (BS / 128) * (D / 128)), 256, 0, stream>>>(a);
        k_attn_w<<<dim3((S / 256) * Bq * H), 512, 0, stream>>>(a);
        k_gemm_out<<<dim3((BS / 128) * (D / 128)), 256, 0, stream>>>(a);
    }
}